// Round 1
// baseline (127.340 us; speedup 1.0000x reference)
//
#include <hip/hip_runtime.h>
#include <math.h>

#define NROOTS 240
#define BLOCK 256

// One thread per token. Roots staged in LDS (broadcast reads).
// weights = softmax(20 * x.r)  [ |x|^2 and |r|^2=1 cancel in softmax ]
// Overflow guard: dot <= |x| since |r|=1, so exponent (dot-|x|)*K <= ~0.
__global__ __launch_bounds__(BLOCK) void e8q_kernel(const float* __restrict__ x,
                                                    const float* __restrict__ roots,
                                                    float* __restrict__ out) {
    __shared__ float lr[NROOTS * 8];
    for (int i = threadIdx.x; i < NROOTS * 8; i += BLOCK) lr[i] = roots[i];
    __syncthreads();

    const size_t t = (size_t)blockIdx.x * BLOCK + threadIdx.x;

    const float4* xp = (const float4*)(x + t * 8);
    float4 xv0 = xp[0];
    float4 xv1 = xp[1];
    float xs[8] = {xv0.x, xv0.y, xv0.z, xv0.w, xv1.x, xv1.y, xv1.z, xv1.w};

    float n2 = 0.0f;
#pragma unroll
    for (int j = 0; j < 8; ++j) n2 = fmaf(xs[j], xs[j], n2);
    const float xn = sqrtf(n2);

    const float K = 28.853900817779268f;  // 20 / ln(2)
    const float C = xn * K;               // exponent offset (upper bound)

    float s = 0.0f;
    float acc[8] = {0, 0, 0, 0, 0, 0, 0, 0};

#pragma unroll 4
    for (int k = 0; k < NROOTS; ++k) {
        const float4* rp = (const float4*)(lr + k * 8);
        float4 r0 = rp[0];
        float4 r1 = rp[1];
        float rr[8] = {r0.x, r0.y, r0.z, r0.w, r1.x, r1.y, r1.z, r1.w};

        float dot = 0.0f;
#pragma unroll
        for (int j = 0; j < 8; ++j) dot = fmaf(xs[j], rr[j], dot);

        float e = exp2f(fmaf(dot, K, -C));
        s += e;
#pragma unroll
        for (int j = 0; j < 8; ++j) acc[j] = fmaf(e, rr[j], acc[j]);
    }

    const float inv = 1.0f / s;
    float4 o0 = make_float4(acc[0] * inv, acc[1] * inv, acc[2] * inv, acc[3] * inv);
    float4 o1 = make_float4(acc[4] * inv, acc[5] * inv, acc[6] * inv, acc[7] * inv);
    float4* op = (float4*)(out + t * 8);
    op[0] = o0;
    op[1] = o1;
}

extern "C" void kernel_launch(void* const* d_in, const int* in_sizes, int n_in,
                              void* d_out, int out_size, void* d_ws, size_t ws_size,
                              hipStream_t stream) {
    const float* x = (const float*)d_in[0];
    const float* roots = (const float*)d_in[1];
    float* out = (float*)d_out;

    const int tokens = in_sizes[0] / 8;      // 256*4096 = 1,048,576
    const int grid = tokens / BLOCK;         // 4096

    e8q_kernel<<<grid, BLOCK, 0, stream>>>(x, roots, out);
}

// Round 2
// 17.020 us; speedup vs baseline: 7.4816x; 7.4816x over previous
//
#include <hip/hip_runtime.h>
#include <math.h>

#define BLOCK 256

// Even/odd-parity partial products monoid for type-2 roots.
struct EO { float E, O; };
__device__ __forceinline__ EO mergeEO(EO a, EO b) {
    EO r;
    r.E = fmaf(a.E, b.E, a.O * b.O);
    r.O = fmaf(a.E, b.O, a.O * b.E);
    return r;
}

// weights = softmax(20 * x.r) over the 240 unit-norm E8 roots; output = sum_k w_k r_k.
// Type-1 roots (112): +-1/sqrt2 at coordinate pairs -> rank-1 factorization over per-dim
//   A_i = u_i+v_i, B_i = u_i-v_i with u/v = exp2(+-K1*x_i - C/2).
// Type-2 roots (128): all +-1/(2*sqrt2), even # of minus -> parity-monoid factorization
//   over g/h = exp2(+-K2*x_i - C/8).
// C = K*|x| bounds every exponent <= 0 (|r|=1 -> dot <= |x|): no overflow, stable.
__global__ __launch_bounds__(BLOCK) void e8q_kernel(const float* __restrict__ x,
                                                    float* __restrict__ out) {
    const size_t t = (size_t)blockIdx.x * BLOCK + threadIdx.x;

    const float4* xp = (const float4*)(x + t * 8);
    float4 xv0 = xp[0];
    float4 xv1 = xp[1];
    float xs[8] = {xv0.x, xv0.y, xv0.z, xv0.w, xv1.x, xv1.y, xv1.z, xv1.w};

    float n2 = 0.0f;
#pragma unroll
    for (int j = 0; j < 8; ++j) n2 = fmaf(xs[j], xs[j], n2);
    const float xn = sqrtf(n2);

    const float K1 = 20.402716373275693f;   // (20/ln2)/sqrt(2)
    const float K2 = 10.201358186637847f;   // (20/ln2)/(2*sqrt(2))
    const float C  = 28.853900817779268f * xn;  // (20/ln2)*|x|
    const float Ch = 0.5f * C;
    const float Ce = 0.125f * C;

    float u[8], v[8], A[8], B[8], g[8], h[8];
#pragma unroll
    for (int j = 0; j < 8; ++j) {
        u[j] = __builtin_amdgcn_exp2f(fmaf(K1, xs[j], -Ch));
        v[j] = __builtin_amdgcn_exp2f(fmaf(-K1, xs[j], -Ch));
        A[j] = u[j] + v[j];
        B[j] = u[j] - v[j];
        g[j] = __builtin_amdgcn_exp2f(fmaf(K2, xs[j], -Ce));
        h[j] = __builtin_amdgcn_exp2f(fmaf(-K2, xs[j], -Ce));
    }

    // ---- Type-1: exclude-one sums via prefix+suffix ADDS (no cancelling subtraction)
    float preA[8], sufA[8];
    preA[0] = A[0];
#pragma unroll
    for (int j = 1; j < 8; ++j) preA[j] = preA[j - 1] + A[j];
    sufA[7] = A[7];
#pragma unroll
    for (int j = 6; j >= 0; --j) sufA[j] = sufA[j + 1] + A[j];

    float EA[8];
    EA[0] = sufA[1];
    EA[7] = preA[6];
#pragma unroll
    for (int j = 1; j < 7; ++j) EA[j] = preA[j - 1] + sufA[j + 1];

    float s1 = 0.0f;   // sum_{i<j} A_i A_j  (= all 112 type-1 weights)
#pragma unroll
    for (int j = 0; j < 7; ++j) s1 = fmaf(A[j], sufA[j + 1], s1);

    // ---- Type-2: parity monoid prefix/suffix
    EO pre[8], suf[8];
    pre[0] = {g[0], h[0]};
#pragma unroll
    for (int j = 1; j < 8; ++j) pre[j] = mergeEO(pre[j - 1], {g[j], h[j]});
    suf[7] = {g[7], h[7]};
#pragma unroll
    for (int j = 6; j >= 1; --j) suf[j] = mergeEO({g[j], h[j]}, suf[j + 1]);

    const float s2 = pre[7].E;  // sum of all 128 even-parity weights

    EO ex[8];
    ex[0] = suf[1];
    ex[7] = pre[6];
#pragma unroll
    for (int j = 1; j < 7; ++j) ex[j] = mergeEO(pre[j - 1], suf[j + 1]);

    const float inv = 1.0f / (s1 + s2);
    const float c1 = 0.70710678118654752f * inv;   // 1/sqrt2
    const float c2 = 0.35355339059327376f * inv;   // 1/(2*sqrt2)

    float o[8];
#pragma unroll
    for (int j = 0; j < 8; ++j) {
        float t1 = B[j] * EA[j];
        float t2 = fmaf(g[j], ex[j].E, -(h[j] * ex[j].O));
        o[j] = fmaf(c1, t1, c2 * t2);
    }

    float4* op = (float4*)(out + t * 8);
    op[0] = make_float4(o[0], o[1], o[2], o[3]);
    op[1] = make_float4(o[4], o[5], o[6], o[7]);
}

extern "C" void kernel_launch(void* const* d_in, const int* in_sizes, int n_in,
                              void* d_out, int out_size, void* d_ws, size_t ws_size,
                              hipStream_t stream) {
    const float* x = (const float*)d_in[0];
    float* out = (float*)d_out;

    const int tokens = in_sizes[0] / 8;   // 1,048,576
    const int grid = tokens / BLOCK;      // 4096

    e8q_kernel<<<grid, BLOCK, 0, stream>>>(x, out);
}

// Round 3
// 16.233 us; speedup vs baseline: 7.8447x; 1.0485x over previous
//
#include <hip/hip_runtime.h>
#include <math.h>

#define BLOCK 256

typedef float v4f __attribute__((ext_vector_type(4)));

// Even/odd-parity partial products monoid for type-2 roots.
struct EO { float E, O; };
__device__ __forceinline__ EO mergeEO(EO a, EO b) {
    EO r;
    r.E = fmaf(a.E, b.E, a.O * b.O);
    r.O = fmaf(a.E, b.O, a.O * b.E);
    return r;
}

// weights = softmax(20 * x.r) over the 240 unit-norm E8 roots; out = sum_k w_k r_k.
// Type-1 (112 roots, +-1/sqrt2 pairs): rank-1 factorization via A=u+v, B=u-v,
//   where u = s*g^2, v = s*h^2 (since K1 = 2*K2 and C/2 = C/4 + 2*(C/8)),
//   s = exp2(-C/4) shared across dims -> saves 16 exp2 per token.
// Type-2 (128 roots, even-parity +-1/(2*sqrt2)): parity monoid over (g,h).
// C = (20/ln2)*|x| bounds all exponents (|r|=1 -> dot <= |x|): no overflow.
__global__ __launch_bounds__(BLOCK) void e8q_kernel(const float* __restrict__ x,
                                                    float* __restrict__ out) {
    const size_t t = (size_t)blockIdx.x * BLOCK + threadIdx.x;

    const v4f* xp = (const v4f*)(x + t * 8);
    v4f xv0 = xp[0];
    v4f xv1 = xp[1];
    float xs[8] = {xv0.x, xv0.y, xv0.z, xv0.w, xv1.x, xv1.y, xv1.z, xv1.w};

    float n2 = 0.0f;
#pragma unroll
    for (int j = 0; j < 8; ++j) n2 = fmaf(xs[j], xs[j], n2);
    const float xn = __builtin_amdgcn_sqrtf(n2);

    const float K2 = 10.201358186637847f;       // (20/ln2)/(2*sqrt(2))
    const float C  = 28.853900817779268f * xn;  // (20/ln2)*|x|
    const float Ce = 0.125f * C;
    const float s  = __builtin_amdgcn_exp2f(-0.25f * C);

    float A[8], B[8], g[8], h[8];
#pragma unroll
    for (int j = 0; j < 8; ++j) {
        g[j] = __builtin_amdgcn_exp2f(fmaf(K2, xs[j], -Ce));
        h[j] = __builtin_amdgcn_exp2f(fmaf(-K2, xs[j], -Ce));
        float a = g[j] * g[j];           // = exp2(K1*x_j - C/4)
        float b = h[j] * h[j];
        float sa = s * a;                // = u_j
        A[j] = fmaf(s, b, sa);           // u + v
        B[j] = fmaf(-s, b, sa);          // u - v
    }

    // ---- Type-1: exclude-one sums via prefix+suffix ADDS (no cancelling subtraction)
    float preA[8], sufA[8];
    preA[0] = A[0];
#pragma unroll
    for (int j = 1; j < 8; ++j) preA[j] = preA[j - 1] + A[j];
    sufA[7] = A[7];
#pragma unroll
    for (int j = 6; j >= 0; --j) sufA[j] = sufA[j + 1] + A[j];

    float EA[8];
    EA[0] = sufA[1];
    EA[7] = preA[6];
#pragma unroll
    for (int j = 1; j < 7; ++j) EA[j] = preA[j - 1] + sufA[j + 1];

    float s1 = 0.0f;   // sum_{i<j} A_i A_j  (= all 112 type-1 weights)
#pragma unroll
    for (int j = 0; j < 7; ++j) s1 = fmaf(A[j], sufA[j + 1], s1);

    // ---- Type-2: parity monoid prefix/suffix
    EO pre[8], suf[8];
    pre[0] = {g[0], h[0]};
#pragma unroll
    for (int j = 1; j < 8; ++j) pre[j] = mergeEO(pre[j - 1], {g[j], h[j]});
    suf[7] = {g[7], h[7]};
#pragma unroll
    for (int j = 6; j >= 1; --j) suf[j] = mergeEO({g[j], h[j]}, suf[j + 1]);

    const float s2 = pre[7].E;  // sum of all 128 even-parity weights

    EO ex[8];
    ex[0] = suf[1];
    ex[7] = pre[6];
#pragma unroll
    for (int j = 1; j < 7; ++j) ex[j] = mergeEO(pre[j - 1], suf[j + 1]);

    const float inv = __builtin_amdgcn_rcpf(s1 + s2);
    const float c1 = 0.70710678118654752f * inv;   // 1/sqrt2
    const float c2 = 0.35355339059327376f * inv;   // 1/(2*sqrt2)

    float o[8];
#pragma unroll
    for (int j = 0; j < 8; ++j) {
        float t1 = B[j] * EA[j];
        float t2 = fmaf(g[j], ex[j].E, -(h[j] * ex[j].O));
        o[j] = fmaf(c1, t1, c2 * t2);
    }

    v4f o0 = {o[0], o[1], o[2], o[3]};
    v4f o1 = {o[4], o[5], o[6], o[7]};
    v4f* op = (v4f*)(out + t * 8);
    __builtin_nontemporal_store(o0, op);
    __builtin_nontemporal_store(o1, op + 1);
}

extern "C" void kernel_launch(void* const* d_in, const int* in_sizes, int n_in,
                              void* d_out, int out_size, void* d_ws, size_t ws_size,
                              hipStream_t stream) {
    const float* x = (const float*)d_in[0];
    float* out = (float*)d_out;

    const int tokens = in_sizes[0] / 8;   // 1,048,576
    const int grid = tokens / BLOCK;      // 4096

    e8q_kernel<<<grid, BLOCK, 0, stream>>>(x, out);
}

// Round 4
// 15.454 us; speedup vs baseline: 8.2400x; 1.0504x over previous
//
#include <hip/hip_runtime.h>
#include <math.h>

#define BLOCK 256
#define TPT 2   // tokens per thread

typedef float v4f __attribute__((ext_vector_type(4)));

// Even/odd-parity partial products monoid for type-2 roots.
struct EO { float E, O; };
__device__ __forceinline__ EO mergeEO(EO a, EO b) {
    EO r;
    r.E = fmaf(a.E, b.E, a.O * b.O);
    r.O = fmaf(a.E, b.O, a.O * b.E);
    return r;
}

// One-token pipeline: weights = softmax(20 * x.r) over 240 unit-norm E8 roots,
// computed in closed form (O(8), no root loop):
//  Type-1 (112): rank-1 factorization A=u+v, B=u-v, u=s*g^2, v=s*h^2
//  Type-2 (128): even-parity monoid over (g,h)
//  g/h = exp2(+-K2*x_j - C/8), s = exp2(-C/4), C = (20/ln2)*|x| (bounds all exps <= 0).
__device__ __forceinline__ void e8q_token(const float xs[8], float o[8]) {
    float n2 = 0.0f;
#pragma unroll
    for (int j = 0; j < 8; ++j) n2 = fmaf(xs[j], xs[j], n2);
    const float xn = __builtin_amdgcn_sqrtf(n2);

    const float K2 = 10.201358186637847f;       // (20/ln2)/(2*sqrt(2))
    const float C  = 28.853900817779268f * xn;  // (20/ln2)*|x|
    const float Ce = 0.125f * C;
    const float s  = __builtin_amdgcn_exp2f(-0.25f * C);

    float A[8], B[8], g[8], h[8];
#pragma unroll
    for (int j = 0; j < 8; ++j) {
        g[j] = __builtin_amdgcn_exp2f(fmaf(K2, xs[j], -Ce));
        h[j] = __builtin_amdgcn_exp2f(fmaf(-K2, xs[j], -Ce));
        float a = g[j] * g[j];
        float b = h[j] * h[j];
        float sa = s * a;                // u_j
        A[j] = fmaf(s, b, sa);           // u + v
        B[j] = fmaf(-s, b, sa);          // u - v
    }

    // Type-1: exclude-one sums via prefix+suffix adds (no cancelling subtraction)
    float preA[8], sufA[8];
    preA[0] = A[0];
#pragma unroll
    for (int j = 1; j < 8; ++j) preA[j] = preA[j - 1] + A[j];
    sufA[7] = A[7];
#pragma unroll
    for (int j = 6; j >= 0; --j) sufA[j] = sufA[j + 1] + A[j];

    float EA[8];
    EA[0] = sufA[1];
    EA[7] = preA[6];
#pragma unroll
    for (int j = 1; j < 7; ++j) EA[j] = preA[j - 1] + sufA[j + 1];

    float s1 = 0.0f;
#pragma unroll
    for (int j = 0; j < 7; ++j) s1 = fmaf(A[j], sufA[j + 1], s1);

    // Type-2: parity monoid prefix/suffix
    EO pre[8], suf[8];
    pre[0] = {g[0], h[0]};
#pragma unroll
    for (int j = 1; j < 8; ++j) pre[j] = mergeEO(pre[j - 1], {g[j], h[j]});
    suf[7] = {g[7], h[7]};
#pragma unroll
    for (int j = 6; j >= 1; --j) suf[j] = mergeEO({g[j], h[j]}, suf[j + 1]);

    const float s2 = pre[7].E;

    EO ex[8];
    ex[0] = suf[1];
    ex[7] = pre[6];
#pragma unroll
    for (int j = 1; j < 7; ++j) ex[j] = mergeEO(pre[j - 1], suf[j + 1]);

    const float inv = __builtin_amdgcn_rcpf(s1 + s2);
    const float c1 = 0.70710678118654752f * inv;   // 1/sqrt2
    const float c2 = 0.35355339059327376f * inv;   // 1/(2*sqrt2)

#pragma unroll
    for (int j = 0; j < 8; ++j) {
        float t1 = B[j] * EA[j];
        float t2 = fmaf(g[j], ex[j].E, -(h[j] * ex[j].O));
        o[j] = fmaf(c1, t1, c2 * t2);
    }
}

__global__ __launch_bounds__(BLOCK) void e8q_kernel(const float* __restrict__ x,
                                                    float* __restrict__ out) {
    const size_t base = (size_t)blockIdx.x * (BLOCK * TPT) + threadIdx.x;

    // Issue all loads up front (4x dwordx4) for memory-level parallelism.
    v4f xv[TPT][2];
#pragma unroll
    for (int p = 0; p < TPT; ++p) {
        const v4f* xp = (const v4f*)(x + (base + (size_t)p * BLOCK) * 8);
        xv[p][0] = xp[0];
        xv[p][1] = xp[1];
    }

#pragma unroll
    for (int p = 0; p < TPT; ++p) {
        float xs[8] = {xv[p][0].x, xv[p][0].y, xv[p][0].z, xv[p][0].w,
                       xv[p][1].x, xv[p][1].y, xv[p][1].z, xv[p][1].w};
        float o[8];
        e8q_token(xs, o);

        v4f o0 = {o[0], o[1], o[2], o[3]};
        v4f o1 = {o[4], o[5], o[6], o[7]};
        v4f* op = (v4f*)(out + (base + (size_t)p * BLOCK) * 8);
        __builtin_nontemporal_store(o0, op);
        __builtin_nontemporal_store(o1, op + 1);
    }
}

extern "C" void kernel_launch(void* const* d_in, const int* in_sizes, int n_in,
                              void* d_out, int out_size, void* d_ws, size_t ws_size,
                              hipStream_t stream) {
    const float* x = (const float*)d_in[0];
    float* out = (float*)d_out;

    const int tokens = in_sizes[0] / 8;        // 1,048,576
    const int grid = tokens / (BLOCK * TPT);   // 2048

    e8q_kernel<<<grid, BLOCK, 0, stream>>>(x, out);
}

// Round 5
// 15.393 us; speedup vs baseline: 8.2728x; 1.0040x over previous
//
#include <hip/hip_runtime.h>
#include <math.h>

#define BLOCK 256
#define TPT 4   // tokens per thread

typedef float v4f __attribute__((ext_vector_type(4)));

// Even/odd-parity partial products monoid for type-2 roots.
struct EO { float E, O; };
__device__ __forceinline__ EO mergeEO(EO a, EO b) {
    EO r;
    r.E = fmaf(a.E, b.E, a.O * b.O);
    r.O = fmaf(a.E, b.O, a.O * b.E);
    return r;
}

// One-token pipeline: weights = softmax(20 * x.r) over 240 unit-norm E8 roots,
// computed in closed form (O(8), no root loop):
//  Type-1 (112): rank-1 factorization A=u+v, B=u-v, u=s*g^2, v=s*h^2
//  Type-2 (128): even-parity monoid over (g,h)
//  g/h = exp2(+-K2*x_j - C/8), s = exp2(-C/4), C = (20/ln2)*|x| (bounds all exps <= 0).
__device__ __forceinline__ void e8q_token(const float xs[8], float o[8]) {
    float n2 = 0.0f;
#pragma unroll
    for (int j = 0; j < 8; ++j) n2 = fmaf(xs[j], xs[j], n2);
    const float xn = __builtin_amdgcn_sqrtf(n2);

    const float K2 = 10.201358186637847f;       // (20/ln2)/(2*sqrt(2))
    const float C  = 28.853900817779268f * xn;  // (20/ln2)*|x|
    const float Ce = 0.125f * C;
    const float s  = __builtin_amdgcn_exp2f(-0.25f * C);

    float A[8], B[8], g[8], h[8];
#pragma unroll
    for (int j = 0; j < 8; ++j) {
        g[j] = __builtin_amdgcn_exp2f(fmaf(K2, xs[j], -Ce));
        h[j] = __builtin_amdgcn_exp2f(fmaf(-K2, xs[j], -Ce));
        float a = g[j] * g[j];
        float b = h[j] * h[j];
        float sa = s * a;                // u_j
        A[j] = fmaf(s, b, sa);           // u + v
        B[j] = fmaf(-s, b, sa);          // u - v
    }

    // Type-1: exclude-one sums via prefix+suffix adds (no cancelling subtraction)
    float preA[8], sufA[8];
    preA[0] = A[0];
#pragma unroll
    for (int j = 1; j < 8; ++j) preA[j] = preA[j - 1] + A[j];
    sufA[7] = A[7];
#pragma unroll
    for (int j = 6; j >= 0; --j) sufA[j] = sufA[j + 1] + A[j];

    float EA[8];
    EA[0] = sufA[1];
    EA[7] = preA[6];
#pragma unroll
    for (int j = 1; j < 7; ++j) EA[j] = preA[j - 1] + sufA[j + 1];

    float s1 = 0.0f;
#pragma unroll
    for (int j = 0; j < 7; ++j) s1 = fmaf(A[j], sufA[j + 1], s1);

    // Type-2: parity monoid prefix/suffix
    EO pre[8], suf[8];
    pre[0] = {g[0], h[0]};
#pragma unroll
    for (int j = 1; j < 8; ++j) pre[j] = mergeEO(pre[j - 1], {g[j], h[j]});
    suf[7] = {g[7], h[7]};
#pragma unroll
    for (int j = 6; j >= 1; --j) suf[j] = mergeEO({g[j], h[j]}, suf[j + 1]);

    const float s2 = pre[7].E;

    EO ex[8];
    ex[0] = suf[1];
    ex[7] = pre[6];
#pragma unroll
    for (int j = 1; j < 7; ++j) ex[j] = mergeEO(pre[j - 1], suf[j + 1]);

    const float inv = __builtin_amdgcn_rcpf(s1 + s2);
    const float c1 = 0.70710678118654752f * inv;   // 1/sqrt2
    const float c2 = 0.35355339059327376f * inv;   // 1/(2*sqrt2)

#pragma unroll
    for (int j = 0; j < 8; ++j) {
        float t1 = B[j] * EA[j];
        float t2 = fmaf(g[j], ex[j].E, -(h[j] * ex[j].O));
        o[j] = fmaf(c1, t1, c2 * t2);
    }
}

__global__ __launch_bounds__(BLOCK, 4) void e8q_kernel(const float* __restrict__ x,
                                                       float* __restrict__ out) {
    const size_t base = (size_t)blockIdx.x * (BLOCK * TPT) + threadIdx.x;

    // Issue ALL loads up front (8x dwordx4) for maximum memory-level parallelism.
    v4f xv[TPT][2];
#pragma unroll
    for (int p = 0; p < TPT; ++p) {
        const v4f* xp = (const v4f*)(x + (base + (size_t)p * BLOCK) * 8);
        xv[p][0] = xp[0];
        xv[p][1] = xp[1];
    }

    // Compute + store each token as soon as its data is consumed (short live ranges;
    // 4 independent dependency chains give the scheduler ILP to hide trans latency).
#pragma unroll
    for (int p = 0; p < TPT; ++p) {
        float xs[8] = {xv[p][0].x, xv[p][0].y, xv[p][0].z, xv[p][0].w,
                       xv[p][1].x, xv[p][1].y, xv[p][1].z, xv[p][1].w};
        float o[8];
        e8q_token(xs, o);

        v4f o0 = {o[0], o[1], o[2], o[3]};
        v4f o1 = {o[4], o[5], o[6], o[7]};
        v4f* op = (v4f*)(out + (base + (size_t)p * BLOCK) * 8);
        __builtin_nontemporal_store(o0, op);
        __builtin_nontemporal_store(o1, op + 1);
    }
}

extern "C" void kernel_launch(void* const* d_in, const int* in_sizes, int n_in,
                              void* d_out, int out_size, void* d_ws, size_t ws_size,
                              hipStream_t stream) {
    const float* x = (const float*)d_in[0];
    float* out = (float*)d_out;

    const int tokens = in_sizes[0] / 8;        // 1,048,576
    const int grid = tokens / (BLOCK * TPT);   // 1024

    e8q_kernel<<<grid, BLOCK, 0, stream>>>(x, out);
}

// Round 6
// 13.958 us; speedup vs baseline: 9.1231x; 1.1028x over previous
//
#include <hip/hip_runtime.h>
#include <math.h>

#define BLOCK 256
#define TPT 2   // tokens per thread; block covers 512 tokens = 1024 float4 slots

typedef float v4f __attribute__((ext_vector_type(4)));

// Even/odd-parity partial products monoid for type-2 roots.
struct EO { float E, O; };
__device__ __forceinline__ EO mergeEO(EO a, EO b) {
    EO r;
    r.E = fmaf(a.E, b.E, a.O * b.O);
    r.O = fmaf(a.E, b.O, a.O * b.E);
    return r;
}

// weights = softmax(20 * x.r) over 240 unit-norm E8 roots, closed form (O(8)):
//  Type-1 (112): rank-1 factorization A=u+v, B=u-v, u=s*g^2, v=s*h^2
//  Type-2 (128): even-parity monoid over (g,h)
//  g/h = exp2(+-K2*x_j - C/8), s = exp2(-C/4), C = (20/ln2)*|x| (all exps <= 0).
__device__ __forceinline__ void e8q_token(const float xs[8], float o[8]) {
    float n2 = 0.0f;
#pragma unroll
    for (int j = 0; j < 8; ++j) n2 = fmaf(xs[j], xs[j], n2);
    const float xn = __builtin_amdgcn_sqrtf(n2);

    const float K2 = 10.201358186637847f;       // (20/ln2)/(2*sqrt(2))
    const float C  = 28.853900817779268f * xn;  // (20/ln2)*|x|
    const float Ce = 0.125f * C;
    const float s  = __builtin_amdgcn_exp2f(-0.25f * C);

    float A[8], B[8], g[8], h[8];
#pragma unroll
    for (int j = 0; j < 8; ++j) {
        g[j] = __builtin_amdgcn_exp2f(fmaf(K2, xs[j], -Ce));
        h[j] = __builtin_amdgcn_exp2f(fmaf(-K2, xs[j], -Ce));
        float a = g[j] * g[j];
        float b = h[j] * h[j];
        float sa = s * a;                // u_j
        A[j] = fmaf(s, b, sa);           // u + v
        B[j] = fmaf(-s, b, sa);          // u - v
    }

    // Type-1: exclude-one sums via prefix+suffix adds (no cancelling subtraction)
    float preA[8], sufA[8];
    preA[0] = A[0];
#pragma unroll
    for (int j = 1; j < 8; ++j) preA[j] = preA[j - 1] + A[j];
    sufA[7] = A[7];
#pragma unroll
    for (int j = 6; j >= 0; --j) sufA[j] = sufA[j + 1] + A[j];

    float EA[8];
    EA[0] = sufA[1];
    EA[7] = preA[6];
#pragma unroll
    for (int j = 1; j < 7; ++j) EA[j] = preA[j - 1] + sufA[j + 1];

    float s1 = 0.0f;
#pragma unroll
    for (int j = 0; j < 7; ++j) s1 = fmaf(A[j], sufA[j + 1], s1);

    // Type-2: parity monoid prefix/suffix
    EO pre[8], suf[8];
    pre[0] = {g[0], h[0]};
#pragma unroll
    for (int j = 1; j < 8; ++j) pre[j] = mergeEO(pre[j - 1], {g[j], h[j]});
    suf[7] = {g[7], h[7]};
#pragma unroll
    for (int j = 6; j >= 1; --j) suf[j] = mergeEO({g[j], h[j]}, suf[j + 1]);

    const float s2 = pre[7].E;

    EO ex[8];
    ex[0] = suf[1];
    ex[7] = pre[6];
#pragma unroll
    for (int j = 1; j < 7; ++j) ex[j] = mergeEO(pre[j - 1], suf[j + 1]);

    const float inv = __builtin_amdgcn_rcpf(s1 + s2);
    const float c1 = 0.70710678118654752f * inv;   // 1/sqrt2
    const float c2 = 0.35355339059327376f * inv;   // 1/(2*sqrt2)

#pragma unroll
    for (int j = 0; j < 8; ++j) {
        float t1 = B[j] * EA[j];
        float t2 = fmaf(g[j], ex[j].E, -(h[j] * ex[j].O));
        o[j] = fmaf(c1, t1, c2 * t2);
    }
}

__global__ __launch_bounds__(BLOCK, 4) void e8q_kernel(const float* __restrict__ x,
                                                       float* __restrict__ out) {
    // Split-region staging: lA[t] = first float4 of token t, lB[t] = second.
    // Writes are lane-dense (conflict-free); dense readback is 2-way (free).
    __shared__ v4f lA[BLOCK * TPT];
    __shared__ v4f lB[BLOCK * TPT];

    const int tid = threadIdx.x;
    const size_t tok0 = (size_t)blockIdx.x * (BLOCK * TPT);

    // Issue all loads up front (4x dwordx4) for MLP. Strided reads are fine:
    // L1 absorbs the second half-line touch, lines fetched from L2 once.
    v4f xv[TPT][2];
#pragma unroll
    for (int p = 0; p < TPT; ++p) {
        const v4f* xp = (const v4f*)(x + (tok0 + tid + (size_t)p * BLOCK) * 8);
        xv[p][0] = xp[0];
        xv[p][1] = xp[1];
    }

#pragma unroll
    for (int p = 0; p < TPT; ++p) {
        float xs[8] = {xv[p][0].x, xv[p][0].y, xv[p][0].z, xv[p][0].w,
                       xv[p][1].x, xv[p][1].y, xv[p][1].z, xv[p][1].w};
        float o[8];
        e8q_token(xs, o);

        const int t = tid + p * BLOCK;   // token index within block
        lA[t] = (v4f){o[0], o[1], o[2], o[3]};
        lB[t] = (v4f){o[4], o[5], o[6], o[7]};
    }

    __syncthreads();

    // Dense flush: lane-contiguous float4 slots -> full 128B lines per 8 lanes.
    v4f* outv = (v4f*)out + tok0 * 2;
#pragma unroll
    for (int k = 0; k < 2 * TPT; ++k) {
        const int s = k * BLOCK + tid;             // float4 slot within block
        v4f val = ((s & 1) ? lB : lA)[s >> 1];
        __builtin_nontemporal_store(val, outv + s);
    }
}

extern "C" void kernel_launch(void* const* d_in, const int* in_sizes, int n_in,
                              void* d_out, int out_size, void* d_ws, size_t ws_size,
                              hipStream_t stream) {
    const float* x = (const float*)d_in[0];
    float* out = (float*)d_out;

    const int tokens = in_sizes[0] / 8;        // 1,048,576
    const int grid = tokens / (BLOCK * TPT);   // 2048

    e8q_kernel<<<grid, BLOCK, 0, stream>>>(x, out);
}